// Round 7
// baseline (269.457 us; speedup 1.0000x reference)
//
#include <hip/hip_runtime.h>

#define B_ 16
#define T_ 2048
#define D_ 512
#define GRID_ 512
#define SCALE_LOG2E 0.18033688f   // (1/8) * log2(e)

typedef __bf16 bf16x8 __attribute__((ext_vector_type(8)));
typedef float  f32x4  __attribute__((ext_vector_type(4)));

__device__ inline unsigned short f2bf(float f){
    union { float f; unsigned u; } x; x.f = f;
    unsigned r = x.u + 0x7fffu + ((x.u >> 16) & 1u);   // RNE
    return (unsigned short)(r >> 16);
}

__device__ inline bf16x8 ldfrag(const unsigned short* p){
    uint4 v = *reinterpret_cast<const uint4*>(p);
    return __builtin_bit_cast(bf16x8, v);
}

// Device-scope grid barrier (counters pre-zeroed by init kernel).
// __syncthreads drains the block's vm/lgkm ops; agent-scope acq_rel add
// publishes them (L2 WB) and the acquire spin + post-barrier invalidate
// makes peers' writes visible (G16: cross-XCD needs device scope).
__device__ inline void grid_bar(unsigned* cnt){
    __syncthreads();
    if (threadIdx.x == 0){
        __hip_atomic_fetch_add(cnt, 1u, __ATOMIC_ACQ_REL, __HIP_MEMORY_SCOPE_AGENT);
        while (__hip_atomic_load(cnt, __ATOMIC_ACQUIRE, __HIP_MEMORY_SCOPE_AGENT) < (unsigned)GRID_)
            __builtin_amdgcn_s_sleep(1);
    }
    __syncthreads();
}

// ws layout (bytes):
//   WcT   @ 0       : 144x512 bf16 (64 Wq^T | 64 Wk^T | sumWq | sumWk | sumWv | 13 zero)
//   bsum  @ 147456  : float[16] (Σbq, Σbk, Σbv)
//   Qb    @ 262144  : 32768x64 bf16, pre-scaled by SCALE_LOG2E
//   Kb    @ 4456448 : 32768x64 bf16, masked rows zeroed
//   wvp   @ 8650752 : float[32768] = qmask*vsum
//   num_s @ 8781824 : float[2][32768]  (per-key-half partial numerators)
//   den_s @ 9043968 : float[2][32768]
//   bar   @ 9306112 : unsigned[16]    (grid-barrier counters)

// ---------------- init: build WcT + bsum, zero out + barrier counters ----------------
__global__ void init_kernel(const float* __restrict__ Wq, const float* __restrict__ Wk,
                            const float* __restrict__ Wv, const float* __restrict__ bq,
                            const float* __restrict__ bk, const float* __restrict__ bv,
                            unsigned short* __restrict__ WcT, float* __restrict__ bsum,
                            float* __restrict__ out, unsigned* __restrict__ bar)
{
    int e = blockIdx.x * 256 + threadIdx.x;
    if (e < 16) bar[e] = 0u;
    if (e < 73728){                       // 144*512
        int j = e >> 9, d = e & 511;
        float v;
        if (j < 64)       v = Wq[d * 64 + j];
        else if (j < 128) v = Wk[d * 64 + (j - 64)];
        else if (j < 131){
            const float* src = (j == 128) ? Wq : (j == 129) ? Wk : Wv;
            const float4* p = reinterpret_cast<const float4*>(&src[d * 64]);
            v = 0.f;
            #pragma unroll
            for (int i = 0; i < 16; i++){ float4 t = p[i]; v += (t.x + t.y) + (t.z + t.w); }
        }
        else v = 0.f;
        WcT[j * 512 + d] = f2bf(v);
    } else if (e < 73744){
        int mm = e - 73728;
        float s = 0.f;
        const float* src = (mm == 0) ? bq : (mm == 1) ? bk : bv;
        if (mm < 3){
            const float4* p = reinterpret_cast<const float4*>(src);
            #pragma unroll
            for (int i = 0; i < 16; i++){ float4 t = p[i]; s += (t.x + t.y) + (t.z + t.w); }
        }
        bsum[mm] = s;
    } else if (e < 81936){
        out[e - 73744] = 0.f;             // 8192 floats
    }
}

// ---------------- mega: proj -> [grid bar] -> attn -> [grid bar] -> out --------------
__global__ __launch_bounds__(256, 2) void mega_kernel(
    const float* __restrict__ inp, const unsigned short* __restrict__ WcT,
    const float* __restrict__ bq, const float* __restrict__ bk,
    const float* __restrict__ bsum,
    unsigned short* __restrict__ Qb, unsigned short* __restrict__ Kb,
    float* __restrict__ wvp, float* __restrict__ num_s, float* __restrict__ den_s,
    float* __restrict__ out, unsigned* __restrict__ bar)
{
    __shared__ union {
        struct { __align__(16) unsigned short Af[2][2048];
                 __align__(16) unsigned short Bf[2][4608];
                 float kz[64]; } p;                                  // 26.9 KB
        struct { __align__(16) unsigned short Kf[2][4096]; } a;      // 16 KB
        struct { float csh[32]; } o;
    } U;
    const int tid  = threadIdx.x;
    const int blk  = blockIdx.x;
    const int lane = tid & 63, wvid = tid >> 6;
    const int m = lane & 15, q = lane >> 4;

    // ===================== phase P: projection (round-6 proj verbatim) ==============
    {
        const int r0 = blk * 64;
        const int mh = wvid >> 1, nh = wvid & 1;

        const int ar = tid >> 2, aseg = tid & 3;
        const int a_off = (ar >> 4) * 512 + (aseg * 16 + (ar & 15)) * 8;
        const float* a_src = &inp[(size_t)(r0 + ar) * 512 + aseg * 8];
        const unsigned short* b_src0 = &WcT[(((tid      ) >> 6) * 16 + (tid & 15)) * 512 + ((tid >> 4) & 3) * 8];
        const unsigned short* b_src1 = &WcT[(((tid + 256) >> 6) * 16 + (tid & 15)) * 512 + ((tid >> 4) & 3) * 8];
        const unsigned short* b_src2 = &WcT[(((tid + 512) >> 6) * 16 + (tid & 15)) * 512 + ((tid >> 4) & 3) * 8];
        const int b_off0 = tid * 8, b_off1 = (tid + 256) * 8, b_off2 = (tid + 512) * 8;

        f32x4 acc[5][2];
        #pragma unroll
        for (int t = 0; t < 5; t++){
            acc[t][0] = (f32x4){0.f, 0.f, 0.f, 0.f};
            acc[t][1] = (f32x4){0.f, 0.f, 0.f, 0.f};
        }

        float4 ga0 = *reinterpret_cast<const float4*>(a_src);
        float4 ga1 = *reinterpret_cast<const float4*>(a_src + 4);
        uint4 gb0 = *reinterpret_cast<const uint4*>(b_src0);
        uint4 gb1 = *reinterpret_cast<const uint4*>(b_src1);
        uint4 gb2 = (tid < 64) ? *reinterpret_cast<const uint4*>(b_src2) : (uint4){0,0,0,0};

        const int ntile = 5 - nh;
        const int tbase = nh * 5;

        for (int it = 0; it < 16; it++){
            const int p = it & 1;
            unsigned short* Ab = U.p.Af[p];
            unsigned short* Bb = U.p.Bf[p];
            uint4 pk;
            pk.x = f2bf(ga0.x) | ((unsigned)f2bf(ga0.y) << 16);
            pk.y = f2bf(ga0.z) | ((unsigned)f2bf(ga0.w) << 16);
            pk.z = f2bf(ga1.x) | ((unsigned)f2bf(ga1.y) << 16);
            pk.w = f2bf(ga1.z) | ((unsigned)f2bf(ga1.w) << 16);
            *reinterpret_cast<uint4*>(&Ab[a_off]) = pk;
            *reinterpret_cast<uint4*>(&Bb[b_off0]) = gb0;
            *reinterpret_cast<uint4*>(&Bb[b_off1]) = gb1;
            if (tid < 64) *reinterpret_cast<uint4*>(&Bb[b_off2]) = gb2;
            __syncthreads();
            if (it < 15){
                const int kn = (it + 1) * 32;
                ga0 = *reinterpret_cast<const float4*>(a_src + kn);
                ga1 = *reinterpret_cast<const float4*>(a_src + kn + 4);
                gb0 = *reinterpret_cast<const uint4*>(b_src0 + kn);
                gb1 = *reinterpret_cast<const uint4*>(b_src1 + kn);
                if (tid < 64) gb2 = *reinterpret_cast<const uint4*>(b_src2 + kn);
            }
            bf16x8 a0 = ldfrag(&Ab[(mh * 2    ) * 512 + lane * 8]);
            bf16x8 a1 = ldfrag(&Ab[(mh * 2 + 1) * 512 + lane * 8]);
            #pragma unroll
            for (int t = 0; t < 5; t++){
                if (t < ntile){
                    bf16x8 bfr = ldfrag(&Bb[(tbase + t) * 512 + lane * 8]);
                    acc[t][0] = __builtin_amdgcn_mfma_f32_16x16x32_bf16(a0, bfr, acc[t][0], 0, 0, 0);
                    acc[t][1] = __builtin_amdgcn_mfma_f32_16x16x32_bf16(a1, bfr, acc[t][1], 0, 0, 0);
                }
            }
        }
        __syncthreads();

        if (nh == 1){
            const float bs = bsum[m];
            #pragma unroll
            for (int f = 0; f < 2; f++){
                #pragma unroll
                for (int i = 0; i < 4; i++){
                    int rl = mh * 32 + f * 16 + q * 4 + i;
                    float val = acc[3][f][i] + bs;
                    float qsv = __shfl(val, (lane & 48));
                    float ksv = __shfl(val, (lane & 48) | 1);
                    float vsv = __shfl(val, (lane & 48) | 2);
                    if (m == 0){
                        U.p.kz[rl] = (ksv == 0.f) ? 0.f : 1.f;
                        wvp[(size_t)r0 + rl] = (qsv == 0.f) ? 0.f : vsv;
                    }
                }
            }
        }
        __syncthreads();

        if (nh == 0){
            float bqv[4];
            #pragma unroll
            for (int t = 0; t < 4; t++) bqv[t] = bq[t * 16 + m];
            const float bkv0 = bk[m];
            #pragma unroll
            for (int f = 0; f < 2; f++){
                #pragma unroll
                for (int i = 0; i < 4; i++){
                    int rl = mh * 32 + f * 16 + q * 4 + i;
                    size_t r = (size_t)r0 + rl;
                    float kz = U.p.kz[rl];
                    #pragma unroll
                    for (int t = 0; t < 4; t++)
                        Qb[r * 64 + t * 16 + m] = f2bf((acc[t][f][i] + bqv[t]) * SCALE_LOG2E);
                    Kb[r * 64 + m] = f2bf((acc[4][f][i] + bkv0) * kz);
                }
            }
        } else {
            float bkv[3];
            #pragma unroll
            for (int t = 0; t < 3; t++) bkv[t] = bk[16 + t * 16 + m];
            #pragma unroll
            for (int f = 0; f < 2; f++){
                #pragma unroll
                for (int i = 0; i < 4; i++){
                    int rl = mh * 32 + f * 16 + q * 4 + i;
                    size_t r = (size_t)r0 + rl;
                    float kz = U.p.kz[rl];
                    #pragma unroll
                    for (int t = 0; t < 3; t++)
                        Kb[r * 64 + 16 + t * 16 + m] = f2bf((acc[t][f][i] + bkv[t]) * kz);
                }
            }
        }
    }

    grid_bar(&bar[0]);

    // ===================== phase A: attention reduce (key-half per wave) ============
    {
        const int g  = blk * 4 + wvid;            // 0..2047
        const int z  = g >> 10;                   // key half
        const int bb = (g >> 6) & 15;             // batch (block-uniform)
        const int t0 = (g & 63) * 32;             // wave's 32 q-rows
        const int s0 = z * 1024;
        const size_t base = (size_t)bb * T_;

        const unsigned short* qp = &Qb[(base + t0 + m) * 64 + q * 8];
        bf16x8 a00 = ldfrag(qp),         a01 = ldfrag(qp + 32);
        bf16x8 a10 = ldfrag(qp + 1024),  a11 = ldfrag(qp + 1024 + 32);

        // wave wvid stages chunks 2*wvid, 2*wvid+1 (key rows wvid*16..+16, both halves)
        const unsigned short* ks0 = &Kb[(base + s0 + wvid * 16 + m) * 64 + q * 8];
        const unsigned short* ks1 = ks0 + 32;
        const int ko0 = (wvid * 2) * 512 + lane * 8;
        const int ko1 = ko0 + 512;
        uint4 st0 = *reinterpret_cast<const uint4*>(ks0);
        uint4 st1 = *reinterpret_cast<const uint4*>(ks1);

        float num0[4] = {0,0,0,0}, den0[4] = {0,0,0,0};
        float num1[4] = {0,0,0,0}, den1[4] = {0,0,0,0};

        for (int it = 0; it < 16; it++){
            const int p = it & 1;
            *reinterpret_cast<uint4*>(&U.a.Kf[p][ko0]) = st0;
            *reinterpret_cast<uint4*>(&U.a.Kf[p][ko1]) = st1;
            __syncthreads();
            if (it < 15){
                st0 = *reinterpret_cast<const uint4*>(ks0 + (it + 1) * 4096);
                st1 = *reinterpret_cast<const uint4*>(ks1 + (it + 1) * 4096);
            }
            float w[4];
            #pragma unroll
            for (int st = 0; st < 4; st++) w[st] = wvp[base + s0 + it * 64 + st * 16 + m];
            #pragma unroll
            for (int st = 0; st < 4; st++){
                bf16x8 b0 = ldfrag(&U.a.Kf[p][(st * 2    ) * 512 + lane * 8]);
                bf16x8 b1 = ldfrag(&U.a.Kf[p][(st * 2 + 1) * 512 + lane * 8]);
                f32x4 z0 = (f32x4){0.f,0.f,0.f,0.f};
                z0 = __builtin_amdgcn_mfma_f32_16x16x32_bf16(a00, b0, z0, 0, 0, 0);
                z0 = __builtin_amdgcn_mfma_f32_16x16x32_bf16(a01, b1, z0, 0, 0, 0);
                f32x4 z1 = (f32x4){0.f,0.f,0.f,0.f};
                z1 = __builtin_amdgcn_mfma_f32_16x16x32_bf16(a10, b0, z1, 0, 0, 0);
                z1 = __builtin_amdgcn_mfma_f32_16x16x32_bf16(a11, b1, z1, 0, 0, 0);
                float wst = w[st];
                #pragma unroll
                for (int i = 0; i < 4; i++){
                    float e0 = exp2f(z0[i]);              // scale pre-folded into Qb
                    den0[i] += e0; num0[i] = fmaf(e0, wst, num0[i]);
                    float e1 = exp2f(z1[i]);
                    den1[i] += e1; num1[i] = fmaf(e1, wst, num1[i]);
                }
            }
        }
        #pragma unroll
        for (int s = 1; s < 16; s <<= 1){
            #pragma unroll
            for (int i = 0; i < 4; i++){
                num0[i] += __shfl_xor(num0[i], s); den0[i] += __shfl_xor(den0[i], s);
                num1[i] += __shfl_xor(num1[i], s); den1[i] += __shfl_xor(den1[i], s);
            }
        }
        if (m == 0){
            const size_t zo = (size_t)z * 32768;
            #pragma unroll
            for (int i = 0; i < 4; i++){
                num_s[zo + base + t0 + q * 4 + i]      = num0[i];
                den_s[zo + base + t0 + q * 4 + i]      = den0[i];
                num_s[zo + base + t0 + 16 + q * 4 + i] = num1[i];
                den_s[zo + base + t0 + 16 + q * 4 + i] = den1[i];
            }
        }
    }

    grid_bar(&bar[1]);

    // ===================== phase O: out[b,d] += sum_t inp * c ======================
    #pragma unroll
    for (int j = 0; j < 2; j++){
        const int tile = blk * 2 + j;             // 0..1023
        const int bb = tile >> 6;
        const int t0 = (tile & 63) * 32;
        const size_t base = (size_t)bb * T_;
        __syncthreads();
        if (tid < 32){
            size_t idx = base + t0 + tid;
            float n = num_s[idx] + num_s[32768 + idx];
            float d = den_s[idx] + den_s[32768 + idx];
            U.o.csh[tid] = n / d;
        }
        __syncthreads();
        const float2* ip = reinterpret_cast<const float2*>(inp + (base + t0) * 512);
        float a0 = 0.f, a1 = 0.f;
        #pragma unroll 8
        for (int t = 0; t < 32; t++){
            float ct = U.o.csh[t];
            float2 v = ip[(size_t)t * 256 + tid];
            a0 = fmaf(v.x, ct, a0);
            a1 = fmaf(v.y, ct, a1);
        }
        atomicAdd(&out[bb * 512 + 2 * tid],     a0);
        atomicAdd(&out[bb * 512 + 2 * tid + 1], a1);
    }
}

extern "C" void kernel_launch(void* const* d_in, const int* in_sizes, int n_in,
                              void* d_out, int out_size, void* d_ws, size_t ws_size,
                              hipStream_t stream)
{
    const float* inp = (const float*)d_in[0];
    const float* Wq  = (const float*)d_in[1];
    const float* bq  = (const float*)d_in[2];
    const float* Wk  = (const float*)d_in[3];
    const float* bk  = (const float*)d_in[4];
    const float* Wv  = (const float*)d_in[5];
    const float* bv  = (const float*)d_in[6];
    float* out = (float*)d_out;

    char* ws = (char*)d_ws;
    unsigned short* WcT = (unsigned short*)(ws);
    float* bsum         = (float*)(ws + 147456);
    unsigned short* Qb  = (unsigned short*)(ws + 262144);
    unsigned short* Kb  = (unsigned short*)(ws + 4456448);
    float* wvp          = (float*)(ws + 8650752);
    float* num_s        = (float*)(ws + 8781824);   // 2 x 32768 floats
    float* den_s        = (float*)(ws + 9043968);   // 2 x 32768 floats
    unsigned* bar       = (unsigned*)(ws + 9306112);

    init_kernel<<<321, 256, 0, stream>>>(Wq, Wk, Wv, bq, bk, bv, WcT, bsum, out, bar);
    mega_kernel<<<GRID_, 256, 0, stream>>>(inp, WcT, bq, bk, bsum, Qb, Kb, wvp,
                                           num_s, den_s, out, bar);
}

// Round 8
// 160.061 us; speedup vs baseline: 1.6835x; 1.6835x over previous
//
#include <hip/hip_runtime.h>

#define B_ 16
#define T_ 2048
#define D_ 512
#define SCALE_LOG2E 0.18033688f   // (1/8) * log2(e)

typedef __bf16 bf16x8 __attribute__((ext_vector_type(8)));
typedef float  f32x4  __attribute__((ext_vector_type(4)));

__device__ inline unsigned short f2bf(float f){
    union { float f; unsigned u; } x; x.f = f;
    unsigned r = x.u + 0x7fffu + ((x.u >> 16) & 1u);   // RNE
    return (unsigned short)(r >> 16);
}

__device__ inline bf16x8 ldfrag(const unsigned short* p){
    uint4 v = *reinterpret_cast<const uint4*>(p);
    return __builtin_bit_cast(bf16x8, v);
}

// ws layout (bytes):
//   WcT  @ 0       : 144x512 bf16 (cols: 64 Wq^T | 64 Wk^T | sumWq | sumWk | sumWv | 13 zero)
//   bsum @ 147456  : float[16] (Σbq, Σbk, Σbv)
//   Qb   @ 262144  : 32768x64 bf16, pre-scaled by SCALE_LOG2E
//   Kb   @ 4456448 : 32768x64 bf16, masked rows zeroed
//   wvp  @ 8650752 : float[32768] = qmask*vsum
//   num  @ 8781824 : float[32768]
//   den  @ 8912896 : float[32768]

// ---------------- setup: build WcT + bsum, zero num/den/out --------------------------
__global__ void setup_kernel(const float* __restrict__ Wq, const float* __restrict__ Wk,
                             const float* __restrict__ Wv, const float* __restrict__ bq,
                             const float* __restrict__ bk, const float* __restrict__ bv,
                             unsigned short* __restrict__ WcT, float* __restrict__ bsum,
                             float* __restrict__ numden, float* __restrict__ out)
{
    int e = blockIdx.x * 256 + threadIdx.x;
    if (e < 73728){                       // 144*512
        int j = e >> 9, d = e & 511;
        float v;
        if (j < 64)       v = Wq[d * 64 + j];
        else if (j < 128) v = Wk[d * 64 + (j - 64)];
        else if (j < 131){
            const float* src = (j == 128) ? Wq : (j == 129) ? Wk : Wv;
            const float4* p = reinterpret_cast<const float4*>(&src[d * 64]);
            v = 0.f;
            #pragma unroll
            for (int i = 0; i < 16; i++){ float4 t = p[i]; v += (t.x + t.y) + (t.z + t.w); }
        }
        else v = 0.f;
        WcT[j * 512 + d] = f2bf(v);
    } else if (e < 73744){
        int mm = e - 73728;
        float s = 0.f;
        const float* src = (mm == 0) ? bq : (mm == 1) ? bk : bv;
        if (mm < 3){
            const float4* p = reinterpret_cast<const float4*>(src);
            #pragma unroll
            for (int i = 0; i < 16; i++){ float4 t = p[i]; s += (t.x + t.y) + (t.z + t.w); }
        }
        bsum[mm] = s;
    } else if (e < 139280){
        numden[e - 73744] = 0.f;          // num + den contiguous, 65536 floats
    } else if (e < 147472){
        out[e - 139280] = 0.f;            // 8192 floats
    }
}

// ---------------- proj: (32768 x 512) @ (512 x 144) -> Qb, Kb, wvp -------------------
// M-tile 32, 1024 blocks (4/CU co-residency). Wave (mh,nh): 16 rows x N-half.
// LDS tiles in MFMA fragment order: chunk*1024B + lane*16B (conflict-free reads).
__global__ __launch_bounds__(256) void proj_kernel(
    const float* __restrict__ inp, const unsigned short* __restrict__ WcT,
    const float* __restrict__ bq, const float* __restrict__ bk,
    const float* __restrict__ bsum,
    unsigned short* __restrict__ Qb, unsigned short* __restrict__ Kb,
    float* __restrict__ wvp)
{
    __shared__ __align__(16) unsigned short Af[2 * 512];    // 2 m-chunks x 1KB
    __shared__ __align__(16) unsigned short Bf[9 * 512];    // 9 n-tiles x 1KB
    __shared__ float kzsh[32];
    const int tid  = threadIdx.x;
    const int r0   = blockIdx.x * 32;
    const int lane = tid & 63, wvid = tid >> 6;
    const int m = lane & 15, q = lane >> 4;
    const int mh = wvid >> 1, nh = wvid & 1;

    // A staging: thread -> row ar (0..31), seg aseg (0..7, 4 floats each)
    const int ar = tid >> 3, aseg = tid & 7;
    unsigned short* a_dst = &Af[(ar >> 4) * 512 + ((aseg >> 1) * 16 + (ar & 15)) * 8 + (aseg & 1) * 4];
    const float* a_src = &inp[(size_t)(r0 + ar) * 512 + aseg * 4];
    // B staging: items tid, tid+256, tid+512(<576); item i: tile=i>>6, m=i&15, q=(i>>4)&3
    const unsigned short* b_src0 = &WcT[(((tid      ) >> 6) * 16 + (tid & 15)) * 512 + ((tid >> 4) & 3) * 8];
    const unsigned short* b_src1 = &WcT[(((tid + 256) >> 6) * 16 + (tid & 15)) * 512 + ((tid >> 4) & 3) * 8];
    const unsigned short* b_src2 = &WcT[(((tid + 512) >> 6) * 16 + (tid & 15)) * 512 + ((tid >> 4) & 3) * 8];
    uint4* b_dst0 = reinterpret_cast<uint4*>(&Bf[(tid      ) * 8]);
    uint4* b_dst1 = reinterpret_cast<uint4*>(&Bf[(tid + 256) * 8]);
    uint4* b_dst2 = reinterpret_cast<uint4*>(&Bf[(tid + 512) * 8]);

    f32x4 acc[5];
    #pragma unroll
    for (int t = 0; t < 5; t++) acc[t] = (f32x4){0.f, 0.f, 0.f, 0.f};

    float4 ga = *reinterpret_cast<const float4*>(a_src);
    uint4 gb0 = *reinterpret_cast<const uint4*>(b_src0);
    uint4 gb1 = *reinterpret_cast<const uint4*>(b_src1);
    uint4 gb2 = (tid < 64) ? *reinterpret_cast<const uint4*>(b_src2) : (uint4){0,0,0,0};

    const int ntile = 5 - nh;             // nh=0: tiles 0-4, nh=1: tiles 5-8
    const int tbase = nh * 5;

    for (int kk = 0; kk < 512; kk += 32){
        ushort4 h; h.x = f2bf(ga.x); h.y = f2bf(ga.y); h.z = f2bf(ga.z); h.w = f2bf(ga.w);
        *reinterpret_cast<ushort4*>(a_dst) = h;
        *b_dst0 = gb0;
        *b_dst1 = gb1;
        if (tid < 64) *b_dst2 = gb2;
        __syncthreads();
        if (kk < 480){
            ga  = *reinterpret_cast<const float4*>(a_src + kk + 32);
            gb0 = *reinterpret_cast<const uint4*>(b_src0 + kk + 32);
            gb1 = *reinterpret_cast<const uint4*>(b_src1 + kk + 32);
            if (tid < 64) gb2 = *reinterpret_cast<const uint4*>(b_src2 + kk + 32);
        }
        bf16x8 a = ldfrag(&Af[mh * 512 + lane * 8]);
        #pragma unroll
        for (int t = 0; t < 5; t++){
            if (t < ntile){               // wave-uniform
                bf16x8 bfr = ldfrag(&Bf[(tbase + t) * 512 + lane * 8]);
                acc[t] = __builtin_amdgcn_mfma_f32_16x16x32_bf16(a, bfr, acc[t], 0, 0, 0);
            }
        }
        __syncthreads();
    }

    // epilogue: nh=1 waves own the sums tile (local acc[3] = global tile 8)
    if (nh == 1){
        const float bs = bsum[m];         // m: 0=Σbq 1=Σbk 2=Σbv
        #pragma unroll
        for (int i = 0; i < 4; i++){
            int rl = mh * 16 + q * 4 + i;
            float val = acc[3][i] + bs;
            float qsv = __shfl(val, (lane & 48));
            float ksv = __shfl(val, (lane & 48) | 1);
            float vsv = __shfl(val, (lane & 48) | 2);
            if (m == 0){
                kzsh[rl] = (ksv == 0.f) ? 0.f : 1.f;
                wvp[(size_t)r0 + rl] = (qsv == 0.f) ? 0.f : vsv;
            }
        }
    }
    __syncthreads();

    if (nh == 0){
        float bqv[4];
        #pragma unroll
        for (int t = 0; t < 4; t++) bqv[t] = bq[t * 16 + m];
        const float bkv0 = bk[m];
        #pragma unroll
        for (int i = 0; i < 4; i++){
            int rl = mh * 16 + q * 4 + i;
            size_t r = (size_t)r0 + rl;
            float kz = kzsh[rl];
            #pragma unroll
            for (int t = 0; t < 4; t++)
                Qb[r * 64 + t * 16 + m] = f2bf((acc[t][i] + bqv[t]) * SCALE_LOG2E);
            Kb[r * 64 + m] = f2bf((acc[4][i] + bkv0) * kz);
        }
    } else {
        float bkv[3];
        #pragma unroll
        for (int t = 0; t < 3; t++) bkv[t] = bk[16 + t * 16 + m];
        #pragma unroll
        for (int i = 0; i < 4; i++){
            int rl = mh * 16 + q * 4 + i;
            size_t r = (size_t)r0 + rl;
            float kz = kzsh[rl];
            #pragma unroll
            for (int t = 0; t < 3; t++)
                Kb[r * 64 + 16 + t * 16 + m] = f2bf((acc[t][i] + bkv[t]) * kz);
        }
    }
}

// ---------------- attn: num/den += over key quarter; LDS K tile in frag order --------
__global__ __launch_bounds__(512) void attn_kernel(
    const unsigned short* __restrict__ Qb, const unsigned short* __restrict__ Kb,
    const float* __restrict__ wvp, float* __restrict__ num_g, float* __restrict__ den_g)
{
    __shared__ __align__(16) unsigned short Kf[8 * 512];   // 8 chunks x 1KB (64 keys)
    const int tid = threadIdx.x;
    const int lane = tid & 63, wvid = tid >> 6;            // 8 waves
    const int m = lane & 15, q = lane >> 4;
    const int b  = blockIdx.y;
    const int t0 = blockIdx.x * 256 + wvid * 32;           // wave's 32 query rows
    const int s0 = blockIdx.z * 512;                       // key quarter
    const size_t base = (size_t)b * T_;

    const unsigned short* qp = &Qb[(base + t0 + m) * 64 + q * 8];
    bf16x8 a00 = ldfrag(qp),            a01 = ldfrag(qp + 32);
    bf16x8 a10 = ldfrag(qp + 16 * 64),  a11 = ldfrag(qp + 16 * 64 + 32);

    const unsigned short* ksrc = &Kb[(base + s0 + (wvid >> 1) * 16 + m) * 64 + (wvid & 1) * 32 + q * 8];
    uint4* kdst = reinterpret_cast<uint4*>(&Kf[wvid * 512 + lane * 8]);
    uint4 stg = *reinterpret_cast<const uint4*>(ksrc);

    float num0[4] = {0,0,0,0}, den0[4] = {0,0,0,0};
    float num1[4] = {0,0,0,0}, den1[4] = {0,0,0,0};

    for (int it = 0; it < 8; it++){
        *kdst = stg;
        __syncthreads();
        if (it < 7) stg = *reinterpret_cast<const uint4*>(ksrc + (it + 1) * 64 * 64);
        float w[4];
        #pragma unroll
        for (int st = 0; st < 4; st++) w[st] = wvp[base + s0 + it * 64 + st * 16 + m];
        #pragma unroll
        for (int st = 0; st < 4; st++){
            bf16x8 b0 = ldfrag(&Kf[(st * 2    ) * 512 + lane * 8]);
            bf16x8 b1 = ldfrag(&Kf[(st * 2 + 1) * 512 + lane * 8]);
            f32x4 z0 = (f32x4){0.f,0.f,0.f,0.f};
            z0 = __builtin_amdgcn_mfma_f32_16x16x32_bf16(a00, b0, z0, 0, 0, 0);
            z0 = __builtin_amdgcn_mfma_f32_16x16x32_bf16(a01, b1, z0, 0, 0, 0);
            f32x4 z1 = (f32x4){0.f,0.f,0.f,0.f};
            z1 = __builtin_amdgcn_mfma_f32_16x16x32_bf16(a10, b0, z1, 0, 0, 0);
            z1 = __builtin_amdgcn_mfma_f32_16x16x32_bf16(a11, b1, z1, 0, 0, 0);
            float wst = w[st];
            #pragma unroll
            for (int i = 0; i < 4; i++){
                float e0 = exp2f(z0[i]);                  // scale pre-folded into Qb
                den0[i] += e0; num0[i] = fmaf(e0, wst, num0[i]);
                float e1 = exp2f(z1[i]);
                den1[i] += e1; num1[i] = fmaf(e1, wst, num1[i]);
            }
        }
        __syncthreads();
    }
    #pragma unroll
    for (int s = 1; s < 16; s <<= 1){
        #pragma unroll
        for (int i = 0; i < 4; i++){
            num0[i] += __shfl_xor(num0[i], s); den0[i] += __shfl_xor(den0[i], s);
            num1[i] += __shfl_xor(num1[i], s); den1[i] += __shfl_xor(den1[i], s);
        }
    }
    if (m == 0){
        #pragma unroll
        for (int i = 0; i < 4; i++){
            atomicAdd(&num_g[base + t0 + q * 4 + i],      num0[i]);
            atomicAdd(&den_g[base + t0 + q * 4 + i],      den0[i]);
            atomicAdd(&num_g[base + t0 + 16 + q * 4 + i], num1[i]);
            atomicAdd(&den_g[base + t0 + 16 + q * 4 + i], den1[i]);
        }
    }
}

// ---------------- out: out[b,d] += sum_t inp[b,t,d] * (num/den)[b,t] -----------------
__global__ __launch_bounds__(256) void out_kernel(
    const float* __restrict__ inp, const float* __restrict__ num_g,
    const float* __restrict__ den_g, float* __restrict__ out)
{
    __shared__ float csh[32];
    const int tid = threadIdx.x;
    const int b   = blockIdx.y;
    const int t0  = blockIdx.x * 32;
    const size_t base = (size_t)b * T_;
    if (tid < 32) csh[tid] = num_g[base + t0 + tid] / den_g[base + t0 + tid];
    __syncthreads();
    const float2* ip = reinterpret_cast<const float2*>(inp + (base + t0) * 512);
    float a0 = 0.f, a1 = 0.f;
    #pragma unroll 8
    for (int t = 0; t < 32; t++){
        float ct = csh[t];
        float2 v = ip[(size_t)t * 256 + tid];
        a0 = fmaf(v.x, ct, a0);
        a1 = fmaf(v.y, ct, a1);
    }
    atomicAdd(&out[b * 512 + 2 * tid],     a0);
    atomicAdd(&out[b * 512 + 2 * tid + 1], a1);
}

extern "C" void kernel_launch(void* const* d_in, const int* in_sizes, int n_in,
                              void* d_out, int out_size, void* d_ws, size_t ws_size,
                              hipStream_t stream)
{
    const float* inp = (const float*)d_in[0];
    const float* Wq  = (const float*)d_in[1];
    const float* bq  = (const float*)d_in[2];
    const float* Wk  = (const float*)d_in[3];
    const float* bk  = (const float*)d_in[4];
    const float* Wv  = (const float*)d_in[5];
    const float* bv  = (const float*)d_in[6];
    float* out = (float*)d_out;

    char* ws = (char*)d_ws;
    unsigned short* WcT = (unsigned short*)(ws);
    float* bsum         = (float*)(ws + 147456);
    unsigned short* Qb  = (unsigned short*)(ws + 262144);
    unsigned short* Kb  = (unsigned short*)(ws + 4456448);
    float* wvp          = (float*)(ws + 8650752);
    float* num_g        = (float*)(ws + 8781824);
    float* den_g        = (float*)(ws + 8912896);

    setup_kernel<<<577, 256, 0, stream>>>(Wq, Wk, Wv, bq, bk, bv, WcT, bsum, num_g, out);
    proj_kernel<<<1024, 256, 0, stream>>>(inp, WcT, bq, bk, bsum, Qb, Kb, wvp);
    attn_kernel<<<dim3(8, 16, 4), 512, 0, stream>>>(Qb, Kb, wvp, num_g, den_g);
    out_kernel<<<dim3(64, 16), 256, 0, stream>>>(inp, num_g, den_g, out);
}

// Round 9
// 152.069 us; speedup vs baseline: 1.7719x; 1.0526x over previous
//
#include <hip/hip_runtime.h>

#define B_ 16
#define T_ 2048
#define D_ 512
#define SCALE_LOG2E 0.18033688f   // (1/8) * log2(e)

typedef __bf16 bf16x8 __attribute__((ext_vector_type(8)));
typedef float  f32x4  __attribute__((ext_vector_type(4)));

__device__ inline unsigned short f2bf(float f){
    union { float f; unsigned u; } x; x.f = f;
    unsigned r = x.u + 0x7fffu + ((x.u >> 16) & 1u);   // RNE
    return (unsigned short)(r >> 16);
}

__device__ inline bf16x8 ldfrag(const unsigned short* p){
    uint4 v = *reinterpret_cast<const uint4*>(p);
    return __builtin_bit_cast(bf16x8, v);
}

// ws layout (bytes):
//   WcT  @ 0       : 144x512 bf16 (cols: 64 Wq^T | 64 Wk^T | sumWq | sumWk | sumWv | 13 zero)
//   bsum @ 147456  : float[16] (Σbq, Σbk, Σbv)
//   Qb   @ 262144  : 32768x64 bf16, pre-scaled by SCALE_LOG2E
//   Kb   @ 4456448 : 32768x64 bf16, masked rows zeroed
//   wvp  @ 8650752 : float[32768] = qmask*vsum

// ---------------- setup: build WcT + bsum, zero out ----------------------------------
__global__ void setup_kernel(const float* __restrict__ Wq, const float* __restrict__ Wk,
                             const float* __restrict__ Wv, const float* __restrict__ bq,
                             const float* __restrict__ bk, const float* __restrict__ bv,
                             unsigned short* __restrict__ WcT, float* __restrict__ bsum,
                             float* __restrict__ out)
{
    int e = blockIdx.x * 256 + threadIdx.x;
    if (e < 73728){                       // 144*512
        int j = e >> 9, d = e & 511;
        float v;
        if (j < 64)       v = Wq[d * 64 + j];
        else if (j < 128) v = Wk[d * 64 + (j - 64)];
        else if (j < 131){
            const float* src = (j == 128) ? Wq : (j == 129) ? Wk : Wv;
            const float4* p = reinterpret_cast<const float4*>(&src[d * 64]);
            v = 0.f;
            #pragma unroll
            for (int i = 0; i < 16; i++){ float4 t = p[i]; v += (t.x + t.y) + (t.z + t.w); }
        }
        else v = 0.f;
        WcT[j * 512 + d] = f2bf(v);
    } else if (e < 73744){
        int mm = e - 73728;
        float s = 0.f;
        const float* src = (mm == 0) ? bq : (mm == 1) ? bk : bv;
        if (mm < 3){
            const float4* p = reinterpret_cast<const float4*>(src);
            #pragma unroll
            for (int i = 0; i < 16; i++){ float4 t = p[i]; s += (t.x + t.y) + (t.z + t.w); }
        }
        bsum[mm] = s;
    } else if (e < 81936){
        out[e - 73744] = 0.f;             // 8192 floats
    }
}

// ---------------- proj: (32768 x 512) @ (512 x 144) -> Qb, Kb, wvp (round-5 exact) ---
__global__ __launch_bounds__(256) void proj_kernel(
    const float* __restrict__ inp, const unsigned short* __restrict__ WcT,
    const float* __restrict__ bq, const float* __restrict__ bk,
    const float* __restrict__ bsum,
    unsigned short* __restrict__ Qb, unsigned short* __restrict__ Kb,
    float* __restrict__ wvp)
{
    __shared__ __align__(16) unsigned short Af[4 * 512];    // 4 m-chunks x 1KB
    __shared__ __align__(16) unsigned short Bf[9 * 512];    // 9 n-tiles x 1KB
    __shared__ float kzsh[64];
    const int tid  = threadIdx.x;
    const int r0   = blockIdx.x * 64;
    const int lane = tid & 63, wvid = tid >> 6;
    const int m = lane & 15, q = lane >> 4;
    const int mh = wvid >> 1, nh = wvid & 1;

    const int ar = tid >> 2, aseg = tid & 3;
    unsigned short* a_dst = &Af[(ar >> 4) * 512 + (aseg * 16 + (ar & 15)) * 8];
    const float* a_src = &inp[(size_t)(r0 + ar) * 512 + aseg * 8];
    const unsigned short* b_src0 = &WcT[(((tid      ) >> 6) * 16 + (tid & 15)) * 512 + ((tid >> 4) & 3) * 8];
    const unsigned short* b_src1 = &WcT[(((tid + 256) >> 6) * 16 + (tid & 15)) * 512 + ((tid >> 4) & 3) * 8];
    const unsigned short* b_src2 = &WcT[(((tid + 512) >> 6) * 16 + (tid & 15)) * 512 + ((tid >> 4) & 3) * 8];
    uint4* b_dst0 = reinterpret_cast<uint4*>(&Bf[(tid      ) * 8]);
    uint4* b_dst1 = reinterpret_cast<uint4*>(&Bf[(tid + 256) * 8]);
    uint4* b_dst2 = reinterpret_cast<uint4*>(&Bf[(tid + 512) * 8]);

    f32x4 acc[5][2];
    #pragma unroll
    for (int t = 0; t < 5; t++){
        acc[t][0] = (f32x4){0.f, 0.f, 0.f, 0.f};
        acc[t][1] = (f32x4){0.f, 0.f, 0.f, 0.f};
    }

    float4 ga0 = *reinterpret_cast<const float4*>(a_src);
    float4 ga1 = *reinterpret_cast<const float4*>(a_src + 4);
    uint4 gb0 = *reinterpret_cast<const uint4*>(b_src0);
    uint4 gb1 = *reinterpret_cast<const uint4*>(b_src1);
    uint4 gb2 = (tid < 64) ? *reinterpret_cast<const uint4*>(b_src2) : (uint4){0,0,0,0};

    const int ntile = 5 - nh;             // nh=0: tiles 0-4, nh=1: tiles 5-8
    const int tbase = nh * 5;

    for (int kk = 0; kk < 512; kk += 32){
        uint4 pk;
        pk.x = f2bf(ga0.x) | ((unsigned)f2bf(ga0.y) << 16);
        pk.y = f2bf(ga0.z) | ((unsigned)f2bf(ga0.w) << 16);
        pk.z = f2bf(ga1.x) | ((unsigned)f2bf(ga1.y) << 16);
        pk.w = f2bf(ga1.z) | ((unsigned)f2bf(ga1.w) << 16);
        *reinterpret_cast<uint4*>(a_dst) = pk;
        *b_dst0 = gb0;
        *b_dst1 = gb1;
        if (tid < 64) *b_dst2 = gb2;
        __syncthreads();
        if (kk < 480){
            ga0 = *reinterpret_cast<const float4*>(a_src + kk + 32);
            ga1 = *reinterpret_cast<const float4*>(a_src + kk + 36);
            gb0 = *reinterpret_cast<const uint4*>(b_src0 + kk + 32);
            gb1 = *reinterpret_cast<const uint4*>(b_src1 + kk + 32);
            if (tid < 64) gb2 = *reinterpret_cast<const uint4*>(b_src2 + kk + 32);
        }
        bf16x8 a0 = ldfrag(&Af[(mh * 2    ) * 512 + lane * 8]);
        bf16x8 a1 = ldfrag(&Af[(mh * 2 + 1) * 512 + lane * 8]);
        #pragma unroll
        for (int t = 0; t < 5; t++){
            if (t < ntile){               // wave-uniform
                bf16x8 bfr = ldfrag(&Bf[(tbase + t) * 512 + lane * 8]);
                acc[t][0] = __builtin_amdgcn_mfma_f32_16x16x32_bf16(a0, bfr, acc[t][0], 0, 0, 0);
                acc[t][1] = __builtin_amdgcn_mfma_f32_16x16x32_bf16(a1, bfr, acc[t][1], 0, 0, 0);
            }
        }
        __syncthreads();
    }

    if (nh == 1){
        const float bs = bsum[m];         // m: 0=Σbq 1=Σbk 2=Σbv
        #pragma unroll
        for (int f = 0; f < 2; f++){
            #pragma unroll
            for (int i = 0; i < 4; i++){
                int rl = mh * 32 + f * 16 + q * 4 + i;
                float val = acc[3][f][i] + bs;
                float qsv = __shfl(val, (lane & 48));
                float ksv = __shfl(val, (lane & 48) | 1);
                float vsv = __shfl(val, (lane & 48) | 2);
                if (m == 0){
                    kzsh[rl] = (ksv == 0.f) ? 0.f : 1.f;
                    wvp[(size_t)r0 + rl] = (qsv == 0.f) ? 0.f : vsv;
                }
            }
        }
    }
    __syncthreads();

    if (nh == 0){
        float bqv[4];
        #pragma unroll
        for (int t = 0; t < 4; t++) bqv[t] = bq[t * 16 + m];
        const float bkv0 = bk[m];
        #pragma unroll
        for (int f = 0; f < 2; f++){
            #pragma unroll
            for (int i = 0; i < 4; i++){
                int rl = mh * 32 + f * 16 + q * 4 + i;
                size_t r = (size_t)r0 + rl;
                float kz = kzsh[rl];
                #pragma unroll
                for (int t = 0; t < 4; t++)
                    Qb[r * 64 + t * 16 + m] = f2bf((acc[t][f][i] + bqv[t]) * SCALE_LOG2E);
                Kb[r * 64 + m] = f2bf((acc[4][f][i] + bkv0) * kz);
            }
        }
    } else {
        float bkv[3];
        #pragma unroll
        for (int t = 0; t < 3; t++) bkv[t] = bk[16 + t * 16 + m];
        #pragma unroll
        for (int f = 0; f < 2; f++){
            #pragma unroll
            for (int i = 0; i < 4; i++){
                int rl = mh * 32 + f * 16 + q * 4 + i;
                size_t r = (size_t)r0 + rl;
                float kz = kzsh[rl];
                #pragma unroll
                for (int t = 0; t < 3; t++)
                    Kb[r * 64 + 16 + t * 16 + m] = f2bf((acc[t][f][i] + bkv[t]) * kz);
            }
        }
    }
}

// ---------------- attn_out: full-K per block -> c in LDS -> out contraction ----------
// Block: (b, 128 q-rows), 8 waves; wave w owns rows t0+w*16, loops ALL 2048 keys.
// K tiles double-buffered in frag order (1 barrier/tile). Then out phase in-block.
__global__ __launch_bounds__(512) void attn_out_kernel(
    const float* __restrict__ inp,
    const unsigned short* __restrict__ Qb, const unsigned short* __restrict__ Kb,
    const float* __restrict__ wvp, float* __restrict__ out)
{
    __shared__ __align__(16) unsigned short Kf[2][8 * 512]; // 2 bufs x 8 chunks x 1KB
    __shared__ float csh[128];
    const int tid = threadIdx.x;
    const int lane = tid & 63, wvid = tid >> 6;             // 8 waves
    const int m = lane & 15, q = lane >> 4;
    const int b  = blockIdx.y;
    const int t0 = blockIdx.x * 128;                        // block's 128 q-rows
    const size_t base = (size_t)b * T_;

    // wave's 16 q-rows
    const unsigned short* qp = &Qb[(base + t0 + wvid * 16 + m) * 64 + q * 8];
    bf16x8 a0 = ldfrag(qp), a1 = ldfrag(qp + 32);

    // wave wvid stages chunk wvid: key rows (wvid>>1)*16..+16, k-half (wvid&1)
    const unsigned short* ksrc = &Kb[(base + (wvid >> 1) * 16 + m) * 64 + (wvid & 1) * 32 + q * 8];
    const int k_off = wvid * 512 + lane * 8;
    uint4 stg = *reinterpret_cast<const uint4*>(ksrc);

    float num[4] = {0,0,0,0}, den[4] = {0,0,0,0};

    for (int it = 0; it < 32; it++){
        const int p = it & 1;
        *reinterpret_cast<uint4*>(&Kf[p][k_off]) = stg;
        __syncthreads();                  // dbuf: single barrier per tile
        if (it < 31) stg = *reinterpret_cast<const uint4*>(ksrc + (it + 1) * 4096);
        float w[4];
        #pragma unroll
        for (int st = 0; st < 4; st++) w[st] = wvp[base + it * 64 + st * 16 + m];
        #pragma unroll
        for (int st = 0; st < 4; st++){
            bf16x8 b0 = ldfrag(&Kf[p][(st * 2    ) * 512 + lane * 8]);
            bf16x8 b1 = ldfrag(&Kf[p][(st * 2 + 1) * 512 + lane * 8]);
            f32x4 z = (f32x4){0.f,0.f,0.f,0.f};
            z = __builtin_amdgcn_mfma_f32_16x16x32_bf16(a0, b0, z, 0, 0, 0);
            z = __builtin_amdgcn_mfma_f32_16x16x32_bf16(a1, b1, z, 0, 0, 0);
            float wst = w[st];
            #pragma unroll
            for (int i = 0; i < 4; i++){
                float e = exp2f(z[i]);                    // scale pre-folded into Qb
                den[i] += e;
                num[i] = fmaf(e, wst, num[i]);
            }
        }
    }
    #pragma unroll
    for (int s = 1; s < 16; s <<= 1){
        #pragma unroll
        for (int i = 0; i < 4; i++){
            num[i] += __shfl_xor(num[i], s);
            den[i] += __shfl_xor(den[i], s);
        }
    }
    __syncthreads();                      // Kf no longer needed; csh about to be written
    if (m == 0){
        #pragma unroll
        for (int i = 0; i < 4; i++)
            csh[wvid * 16 + q * 4 + i] = num[i] / den[i];
    }
    __syncthreads();

    // out phase: thread tid owns column tid; loop the block's 128 rows
    const float* ip = inp + (base + t0) * 512 + tid;
    float a = 0.f;
    #pragma unroll 8
    for (int t = 0; t < 128; t++)
        a = fmaf(ip[(size_t)t * 512], csh[t], a);
    atomicAdd(&out[b * 512 + tid], a);
}

extern "C" void kernel_launch(void* const* d_in, const int* in_sizes, int n_in,
                              void* d_out, int out_size, void* d_ws, size_t ws_size,
                              hipStream_t stream)
{
    const float* inp = (const float*)d_in[0];
    const float* Wq  = (const float*)d_in[1];
    const float* bq  = (const float*)d_in[2];
    const float* Wk  = (const float*)d_in[3];
    const float* bk  = (const float*)d_in[4];
    const float* Wv  = (const float*)d_in[5];
    const float* bv  = (const float*)d_in[6];
    float* out = (float*)d_out;

    char* ws = (char*)d_ws;
    unsigned short* WcT = (unsigned short*)(ws);
    float* bsum         = (float*)(ws + 147456);
    unsigned short* Qb  = (unsigned short*)(ws + 262144);
    unsigned short* Kb  = (unsigned short*)(ws + 4456448);
    float* wvp          = (float*)(ws + 8650752);

    setup_kernel<<<321, 256, 0, stream>>>(Wq, Wk, Wv, bq, bk, bv, WcT, bsum, out);
    proj_kernel<<<512, 256, 0, stream>>>(inp, WcT, bq, bk, bsum, Qb, Kb, wvp);
    attn_out_kernel<<<dim3(16, 16), 512, 0, stream>>>(inp, Qb, Kb, wvp, out);
}